// Round 4
// baseline (947.719 us; speedup 1.0000x reference)
//
#include <hip/hip_runtime.h>
#include <hip/hip_bf16.h>
#include <math.h>

// GCN link prediction, fp32. Self-loops analytic:
//   deg[v] = incount(col==v)+1 ; dinv = rsqrt(deg)
//   ts[v]  = (h[v]@W)*dinv[v]
//   h'[c]  = act(dinv[c]*(sum_{e:col=c} ts[row_e] + ts[c]) + b)
//   score  = sigmoid(dot(h2[row], h2[col]))
//
// R3 lesson: random 4B atomic-with-return + random 4B scatter (k_fill) ran at
// 11G edges/s = 285us; random global atomics are the poison. R4: deterministic
// two-level counting sort (bucket = col>>9, 512 nodes/bucket) with NO global
// atomics, then per-bucket LDS-accumulator aggregation (ds_add_f32).

#define BSH 9
#define BSZ 512            // nodes per bucket
#define PA_BLOCKS 256      // edge chunks (must equal pB1 scan width)

// ---- Phase A: per-(chunk,bucket) histogram -> M[b][NBUK] ----
__global__ __launch_bounds__(512) void pA(const int* __restrict__ col,
                                          int* __restrict__ M, int E, int CH, int NBUK) {
    extern __shared__ int hist[];           // NBUK ints
    const int t = threadIdx.x, b = blockIdx.x;
    for (int i = t; i < NBUK; i += 512) hist[i] = 0;
    __syncthreads();
    const int s = b * CH, e = min(E, s + CH);
    for (int i = s + t; i < e; i += 512) atomicAdd(&hist[col[i] >> BSH], 1);
    __syncthreads();
    for (int i = t; i < NBUK; i += 512) M[b * NBUK + i] = hist[i];
}

// ---- Phase B1: per-bucket exclusive scan over the 256 chunks (in place) ----
__global__ __launch_bounds__(256) void pB1(int* __restrict__ M, int* __restrict__ T, int NBUK) {
    __shared__ int s[256];
    const int t = threadIdx.x, k = blockIdx.x;
    int own = M[t * NBUK + k];
    s[t] = own;
    __syncthreads();
    for (int d = 1; d < 256; d <<= 1) {
        int add = (t >= d) ? s[t - d] : 0;
        __syncthreads();
        s[t] += add;
        __syncthreads();
    }
    M[t * NBUK + k] = s[t] - own;           // exclusive
    if (t == 255) T[k] = s[255];
}

// ---- Phase B2: exclusive scan of bucket totals -> S[0..NBUK] ----
__global__ __launch_bounds__(256) void pB2(const int* __restrict__ T, int* __restrict__ S, int NBUK) {
    __shared__ int s[256];
    const int t = threadIdx.x;
    int own = (t < NBUK) ? T[t] : 0;
    s[t] = own;
    __syncthreads();
    for (int d = 1; d < 256; d <<= 1) {
        int add = (t >= d) ? s[t - d] : 0;
        __syncthreads();
        s[t] += add;
        __syncthreads();
    }
    if (t < NBUK) S[t] = s[t] - own;
    if (t == 255) S[NBUK] = s[255];
}

// ---- Phase C: place edges bucket-sorted into ebuf, packed (lcol<<17)|row ----
__global__ __launch_bounds__(512) void pC(const int* __restrict__ row, const int* __restrict__ col,
                                          const int* __restrict__ M, const int* __restrict__ S,
                                          unsigned int* __restrict__ ebuf, int E, int CH, int NBUK) {
    extern __shared__ int cur[];            // NBUK ints
    const int t = threadIdx.x, b = blockIdx.x;
    for (int i = t; i < NBUK; i += 512) cur[i] = S[i] + M[b * NBUK + i];
    __syncthreads();
    const int s = b * CH, e = min(E, s + CH);
    for (int i = s + t; i < e; i += 512) {
        int c = col[i], r = row[i];
        int k = c >> BSH;
        int p = atomicAdd(&cur[k], 1);      // LDS atomic
        ebuf[p] = ((unsigned int)(c & (BSZ - 1)) << 17) | (unsigned int)r;
    }
}

// ---- Phase D: per-bucket degrees -> dinv ----
__global__ __launch_bounds__(512) void pDeg(const unsigned int* __restrict__ ebuf,
                                            const int* __restrict__ S,
                                            float* __restrict__ dinv, int N) {
    __shared__ int h[BSZ];
    const int t = threadIdx.x, k = blockIdx.x;
    h[t] = 0;
    __syncthreads();
    const int s = S[k], e = S[k + 1];
    for (int i = s + t; i < e; i += 512) atomicAdd(&h[ebuf[i] >> 17], 1);
    __syncthreads();
    const int v = (k << BSH) + t;
    if (v < N) dinv[v] = rsqrtf((float)h[t] + 1.0f);
}

// ---- GEMM1: ts[v] = (x[v] @ W1) * dinv[v], one node per thread ----
__global__ __launch_bounds__(256) void k_gemm1(
    const float* __restrict__ x, const float* __restrict__ W1,
    const float* __restrict__ dinv, float* __restrict__ ts, int N) {
    __shared__ float wsT[16 * 132];         // W1^T, stride 132
    const int tid = threadIdx.x;
    for (int idx = tid; idx < 2048; idx += 256) {
        int k = idx >> 4, c = idx & 15;
        wsT[c * 132 + k] = W1[idx];
    }
    __syncthreads();
    const int n = blockIdx.x * 256 + tid;
    if (n >= N) return;
    const float4* xr = (const float4*)(x + (size_t)n * 128);
    float acc[16];
    #pragma unroll
    for (int c = 0; c < 16; ++c) acc[c] = 0.f;
    #pragma unroll 4
    for (int k4 = 0; k4 < 32; ++k4) {
        float4 a = xr[k4];
        #pragma unroll
        for (int c = 0; c < 16; ++c) {
            const float4 w = *(const float4*)&wsT[c * 132 + k4 * 4];
            acc[c] = fmaf(a.x, w.x, fmaf(a.y, w.y, fmaf(a.z, w.z, fmaf(a.w, w.w, acc[c]))));
        }
    }
    float dv = dinv[n];
    float4* o = (float4*)(ts + (size_t)n * 16);
    #pragma unroll
    for (int q = 0; q < 4; ++q)
        o[q] = make_float4(acc[4*q] * dv, acc[4*q+1] * dv, acc[4*q+2] * dv, acc[4*q+3] * dv);
}

// ---- Aggregation layer 1: LDS accumulate + bias/ReLU + fused 16x16 W2 ----
__global__ __launch_bounds__(1024) void pAgg1(
    const unsigned int* __restrict__ ebuf, const int* __restrict__ S,
    const float* __restrict__ ts_in, const float* __restrict__ dinv,
    const float* __restrict__ b1, const float* __restrict__ W2,
    float* __restrict__ out, int N) {
    __shared__ float acc[BSZ * 16];         // 32 KB
    __shared__ float w2s[256];
    const int tid = threadIdx.x;
    const int lane = tid & 15, g = tid >> 4;     // 64 groups of 16
    for (int i = tid; i < BSZ * 16; i += 1024) acc[i] = 0.f;
    if (tid < 256) w2s[tid] = W2[tid];
    const float bc = b1[lane];
    __syncthreads();

    const int k = blockIdx.x;
    const int s = S[k], e = S[k + 1];
    for (int base = s; base + g < e; base += 128) {
        int i0 = base + g, i1 = i0 + 64;
        unsigned int w0 = ebuf[i0];
        bool has1 = i1 < e;
        unsigned int w1 = has1 ? ebuf[i1] : 0u;
        int r0 = w0 & 0x1FFFF, c0 = w0 >> 17;
        float v0 = ts_in[(size_t)r0 * 16 + lane];
        int c1 = 0; float v1 = 0.f;
        if (has1) { int r1 = w1 & 0x1FFFF; c1 = w1 >> 17; v1 = ts_in[(size_t)r1 * 16 + lane]; }
        atomicAdd(&acc[c0 * 16 + lane], v0);
        if (has1) atomicAdd(&acc[c1 * 16 + lane], v1);
    }
    __syncthreads();

    for (int l = g; l < BSZ; l += 64) {
        int v = (k << BSH) + l;
        if (v < N) {
            float dv = dinv[v];
            float a = acc[l * 16 + lane] + ts_in[(size_t)v * 16 + lane];
            float h = fmaxf(dv * a + bc, 0.f);
            float o = 0.f;
            #pragma unroll
            for (int j = 0; j < 16; ++j)
                o = fmaf(__shfl(h, j, 16), w2s[j * 16 + lane], o);
            out[(size_t)v * 16 + lane] = dv * o;
        }
    }
}

// ---- Aggregation layer 2: LDS accumulate + bias -> h2 ----
__global__ __launch_bounds__(1024) void pAgg2(
    const unsigned int* __restrict__ ebuf, const int* __restrict__ S,
    const float* __restrict__ ts_in, const float* __restrict__ dinv,
    const float* __restrict__ b2, float* __restrict__ out, int N) {
    __shared__ float acc[BSZ * 16];
    const int tid = threadIdx.x;
    const int lane = tid & 15, g = tid >> 4;
    for (int i = tid; i < BSZ * 16; i += 1024) acc[i] = 0.f;
    const float bc = b2[lane];
    __syncthreads();

    const int k = blockIdx.x;
    const int s = S[k], e = S[k + 1];
    for (int base = s; base + g < e; base += 128) {
        int i0 = base + g, i1 = i0 + 64;
        unsigned int w0 = ebuf[i0];
        bool has1 = i1 < e;
        unsigned int w1 = has1 ? ebuf[i1] : 0u;
        int r0 = w0 & 0x1FFFF, c0 = w0 >> 17;
        float v0 = ts_in[(size_t)r0 * 16 + lane];
        int c1 = 0; float v1 = 0.f;
        if (has1) { int r1 = w1 & 0x1FFFF; c1 = w1 >> 17; v1 = ts_in[(size_t)r1 * 16 + lane]; }
        atomicAdd(&acc[c0 * 16 + lane], v0);
        if (has1) atomicAdd(&acc[c1 * 16 + lane], v1);
    }
    __syncthreads();

    for (int l = g; l < BSZ; l += 64) {
        int v = (k << BSH) + l;
        if (v < N)
            out[(size_t)v * 16 + lane] =
                dinv[v] * (acc[l * 16 + lane] + ts_in[(size_t)v * 16 + lane]) + bc;
    }
}

// ---- Edge scores ----
__global__ void k_score(const int* __restrict__ row, const int* __restrict__ col,
                        const float* __restrict__ h2, float* __restrict__ out, int E) {
    int e = blockIdx.x * 256 + threadIdx.x;
    if (e < E) {
        const float4* a = (const float4*)(h2 + (size_t)row[e] * 16);
        const float4* b = (const float4*)(h2 + (size_t)col[e] * 16);
        float d = 0.f;
        #pragma unroll
        for (int i = 0; i < 4; ++i) {
            float4 u = a[i], v = b[i];
            d += u.x * v.x + u.y * v.y + u.z * v.z + u.w * v.w;
        }
        out[e] = 1.0f / (1.0f + __expf(-d));
    }
}

// ---------------- Fallback (R2 atomic path) ----------------
__global__ void k_countf(const int* __restrict__ col, float* __restrict__ deg, int E) {
    int e = blockIdx.x * 256 + threadIdx.x;
    if (e < E) atomicAdd(&deg[col[e]], 1.0f);
}
__global__ void k_dinvf(float* __restrict__ dinv, int N) {
    int v = blockIdx.x * 256 + threadIdx.x;
    if (v < N) dinv[v] = rsqrtf(dinv[v] + 1.0f);
}
__global__ void k_scatter(const int* __restrict__ row, const int* __restrict__ col,
                          const float* __restrict__ ts, float* __restrict__ acc, int E) {
    int g = blockIdx.x * 256 + threadIdx.x;
    int e = g >> 4, c = g & 15;
    if (e < E) atomicAdd(&acc[(size_t)col[e] * 16 + c], ts[(size_t)row[e] * 16 + c]);
}
__global__ void k_finalize(float* __restrict__ acc, const float* __restrict__ ts,
                           const float* __restrict__ dinv, const float* __restrict__ b,
                           int N, int relu) {
    int g = blockIdx.x * 256 + threadIdx.x;
    int v = g >> 4, c = g & 15;
    if (v < N) {
        float h = dinv[v] * (acc[g] + ts[g]) + b[c];
        if (relu) h = fmaxf(h, 0.f);
        acc[g] = h;
    }
}
__global__ __launch_bounds__(256) void k_gemm2f(
    const float* __restrict__ h1, const float* __restrict__ W2,
    const float* __restrict__ dinv, float* __restrict__ ts2, int N) {
    __shared__ float hs[16 * 17];
    __shared__ float ws[256];
    const int tid = threadIdx.x;
    const int base = blockIdx.x * 16;
    if (tid < 64) ((float4*)ws)[tid] = ((const float4*)W2)[tid];
    if (tid >= 64 && tid < 128) {
        int t2 = tid - 64;
        float4 v4 = ((const float4*)(h1 + (size_t)base * 16))[t2];
        float* d = &hs[(t2 >> 2) * 17 + (t2 & 3) * 4];
        d[0] = v4.x; d[1] = v4.y; d[2] = v4.z; d[3] = v4.w;
    }
    __syncthreads();
    const int r = tid >> 4, c = tid & 15;
    float a = 0.f;
    #pragma unroll
    for (int kk = 0; kk < 16; ++kk) a = fmaf(hs[r * 17 + kk], ws[kk * 16 + c], a);
    ts2[(size_t)(base + r) * 16 + c] = a * dinv[base + r];
}

extern "C" void kernel_launch(void* const* d_in, const int* in_sizes, int n_in,
                              void* d_out, int out_size, void* d_ws, size_t ws_size,
                              hipStream_t stream) {
    const float* x  = (const float*)d_in[0];
    const int*   ei = (const int*)d_in[1];
    const float* W1 = (const float*)d_in[2];
    const float* b1 = (const float*)d_in[3];
    const float* W2 = (const float*)d_in[4];
    const float* b2 = (const float*)d_in[5];

    const int N = in_sizes[0] / 128;   // 100000
    const int E = in_sizes[1] / 2;     // 3200000
    const int* row = ei;
    const int* col = ei + E;
    float* out = (float*)d_out;

    const int NBUK = (N + BSZ - 1) / BSZ;   // 196
    const int CH = (E + PA_BLOCKS - 1) / PA_BLOCKS;

    // workspace layout (16B-aligned chunks)
    char* ws = (char*)d_ws;
    size_t off = 0;
    auto alloc = [&](size_t bytes) { void* p = ws + off; off += (bytes + 15) & ~(size_t)15; return p; };
    float* dinv = (float*)alloc((size_t)N * 4);
    float* ts1  = (float*)alloc((size_t)N * 64);     // gemm1 out; later h2
    float* ts2  = (float*)alloc((size_t)N * 64);
    int*   M    = (int*)alloc((size_t)PA_BLOCKS * NBUK * 4);
    int*   T    = (int*)alloc((size_t)NBUK * 4);
    int*   S    = (int*)alloc((size_t)(NBUK + 1) * 4);
    unsigned int* ebuf = (unsigned int*)alloc((size_t)E * 4);
    const size_t need = off;

    if (N < 131072 && NBUK <= 256 && ws_size >= need) {
        size_t ldsA = (size_t)NBUK * 4;
        pA <<<PA_BLOCKS, 512, ldsA, stream>>>(col, M, E, CH, NBUK);
        pB1<<<NBUK, 256, 0, stream>>>(M, T, NBUK);
        pB2<<<1, 256, 0, stream>>>(T, S, NBUK);
        pC <<<PA_BLOCKS, 512, ldsA, stream>>>(row, col, M, S, ebuf, E, CH, NBUK);
        pDeg<<<NBUK, 512, 0, stream>>>(ebuf, S, dinv, N);
        k_gemm1<<<(N + 255) / 256, 256, 0, stream>>>(x, W1, dinv, ts1, N);
        pAgg1<<<NBUK, 1024, 0, stream>>>(ebuf, S, ts1, dinv, b1, W2, ts2, N);
        pAgg2<<<NBUK, 1024, 0, stream>>>(ebuf, S, ts2, dinv, b2, ts1, N);
        k_score<<<(E + 255) / 256, 256, 0, stream>>>(row, col, ts1, out, E);
    } else {
        // R2 atomic fallback
        hipMemsetAsync(dinv, 0, (size_t)N * 4, stream);
        hipMemsetAsync(ts2, 0, (size_t)N * 64, stream);
        k_countf<<<(E + 255) / 256, 256, 0, stream>>>(col, dinv, E);
        k_dinvf<<<(N + 255) / 256, 256, 0, stream>>>(dinv, N);
        k_gemm1<<<(N + 255) / 256, 256, 0, stream>>>(x, W1, dinv, ts1, N);
        k_scatter<<<(E * 16) / 256, 256, 0, stream>>>(row, col, ts1, ts2, E);
        k_finalize<<<(N * 16 + 255) / 256, 256, 0, stream>>>(ts2, ts1, dinv, b1, N, 1);
        k_gemm2f<<<N / 16, 256, 0, stream>>>(ts2, W2, dinv, ts1, N);
        hipMemsetAsync(ts2, 0, (size_t)N * 64, stream);
        k_scatter<<<(E * 16) / 256, 256, 0, stream>>>(row, col, ts1, ts2, E);
        k_finalize<<<(N * 16 + 255) / 256, 256, 0, stream>>>(ts2, ts1, dinv, b2, N, 0);
        k_score<<<(E + 255) / 256, 256, 0, stream>>>(row, col, ts2, out, E);
    }
}

// Round 5
// 819.025 us; speedup vs baseline: 1.1571x; 1.1571x over previous
//
#include <hip/hip_runtime.h>
#include <hip/hip_bf16.h>
#include <hip/hip_fp16.h>
#include <math.h>

// GCN link prediction. R5: bucket-sorted edges (no global atomics in build),
// fp16 gather tables (3.2MB -> per-XCD-L2-resident), sliced bucket aggregation
// (196x8 blocks) with LDS fp32 accumulators + coalesced atomic flush.
//   deg[v] = incount(col==v)+1 ; dinv = rsqrt(deg)
//   ts[v]  = (h[v]@W)*dinv[v]          (fp16 table)
//   h'[c]  = act(dinv[c]*(sum_{e:col=c} ts[row_e] + ts[c]) + b)
//   score  = sigmoid(dot(h2[row], h2[col]))

#define BSH 9
#define BSZ 512
#define PA_BLOCKS 256
#define ZSL 8            // slices per bucket

static __device__ __forceinline__ void gAtomicAdd(float* p, float v) {
#if defined(__HIP_DEVICE_COMPILE__)
    unsafeAtomicAdd(p, v);   // global_atomic_add_f32
#else
    atomicAdd(p, v);
#endif
}

// ---- Phase A: per-(chunk,bucket) histogram -> M[b][NBUK] ----
__global__ __launch_bounds__(512) void pA(const int* __restrict__ col,
                                          int* __restrict__ M, int E, int CH, int NBUK) {
    extern __shared__ int hist[];
    const int t = threadIdx.x, b = blockIdx.x;
    for (int i = t; i < NBUK; i += 512) hist[i] = 0;
    __syncthreads();
    const int s = b * CH, e = min(E, s + CH);
    for (int i = s + t; i < e; i += 512) atomicAdd(&hist[col[i] >> BSH], 1);
    __syncthreads();
    for (int i = t; i < NBUK; i += 512) M[b * NBUK + i] = hist[i];
}

// ---- Phase B1: per-bucket exclusive scan over chunks ----
__global__ __launch_bounds__(256) void pB1(int* __restrict__ M, int* __restrict__ T, int NBUK) {
    __shared__ int s[256];
    const int t = threadIdx.x, k = blockIdx.x;
    int own = M[t * NBUK + k];
    s[t] = own;
    __syncthreads();
    for (int d = 1; d < 256; d <<= 1) {
        int add = (t >= d) ? s[t - d] : 0;
        __syncthreads();
        s[t] += add;
        __syncthreads();
    }
    M[t * NBUK + k] = s[t] - own;
    if (t == 255) T[k] = s[255];
}

// ---- Phase B2: exclusive scan of bucket totals -> S[0..NBUK] ----
__global__ __launch_bounds__(256) void pB2(const int* __restrict__ T, int* __restrict__ S, int NBUK) {
    __shared__ int s[256];
    const int t = threadIdx.x;
    int own = (t < NBUK) ? T[t] : 0;
    s[t] = own;
    __syncthreads();
    for (int d = 1; d < 256; d <<= 1) {
        int add = (t >= d) ? s[t - d] : 0;
        __syncthreads();
        s[t] += add;
        __syncthreads();
    }
    if (t < NBUK) S[t] = s[t] - own;
    if (t == 255) S[NBUK] = s[255];
}

// ---- Phase C: place edges into ebuf, packed (lcol<<17)|row ----
__global__ __launch_bounds__(512) void pC(const int* __restrict__ row, const int* __restrict__ col,
                                          const int* __restrict__ M, const int* __restrict__ S,
                                          unsigned int* __restrict__ ebuf, int E, int CH, int NBUK) {
    extern __shared__ int cur[];
    const int t = threadIdx.x, b = blockIdx.x;
    for (int i = t; i < NBUK; i += 512) cur[i] = S[i] + M[b * NBUK + i];
    __syncthreads();
    const int s = b * CH, e = min(E, s + CH);
    for (int i = s + t; i < e; i += 512) {
        int c = col[i], r = row[i];
        int p = atomicAdd(&cur[c >> BSH], 1);
        ebuf[p] = ((unsigned int)(c & (BSZ - 1)) << 17) | (unsigned int)r;
    }
}

// ---- Phase D: degrees -> dinv ----
__global__ __launch_bounds__(512) void pDeg(const unsigned int* __restrict__ ebuf,
                                            const int* __restrict__ S,
                                            float* __restrict__ dinv, int N) {
    __shared__ int h[BSZ];
    const int t = threadIdx.x, k = blockIdx.x;
    h[t] = 0;
    __syncthreads();
    const int s = S[k], e = S[k + 1];
    for (int i = s + t; i < e; i += 512) atomicAdd(&h[ebuf[i] >> 17], 1);
    __syncthreads();
    const int v = (k << BSH) + t;
    if (v < N) dinv[v] = rsqrtf((float)h[t] + 1.0f);
}

// ---- GEMM1: ts1h[v] = half((x[v] @ W1) * dinv[v]) ----
__global__ __launch_bounds__(256) void k_gemm1(
    const float* __restrict__ x, const float* __restrict__ W1,
    const float* __restrict__ dinv, __half* __restrict__ ts, int N) {
    __shared__ float wsT[16 * 132];
    const int tid = threadIdx.x;
    for (int idx = tid; idx < 2048; idx += 256) {
        int k = idx >> 4, c = idx & 15;
        wsT[c * 132 + k] = W1[idx];
    }
    __syncthreads();
    const int n = blockIdx.x * 256 + tid;
    if (n >= N) return;
    const float4* xr = (const float4*)(x + (size_t)n * 128);
    float acc[16];
    #pragma unroll
    for (int c = 0; c < 16; ++c) acc[c] = 0.f;
    #pragma unroll 4
    for (int k4 = 0; k4 < 32; ++k4) {
        float4 a = xr[k4];
        #pragma unroll
        for (int c = 0; c < 16; ++c) {
            const float4 w = *(const float4*)&wsT[c * 132 + k4 * 4];
            acc[c] = fmaf(a.x, w.x, fmaf(a.y, w.y, fmaf(a.z, w.z, fmaf(a.w, w.w, acc[c]))));
        }
    }
    float dv = dinv[n];
    union { __half h[16]; uint4 u[2]; } o;
    #pragma unroll
    for (int c = 0; c < 16; ++c) o.h[c] = __float2half(acc[c] * dv);
    uint4* dst = (uint4*)(ts + (size_t)n * 16);
    dst[0] = o.u[0]; dst[1] = o.u[1];
}

// ---- Sliced aggregation: partial sums of ts[row] into global acc[col] ----
__global__ __launch_bounds__(256) void pAgg(
    const unsigned int* __restrict__ ebuf, const int* __restrict__ S,
    const __half* __restrict__ tsh, float* __restrict__ accg, int N) {
    __shared__ float accl[BSZ * 16];          // 32 KB
    const int tid = threadIdx.x;
    const int lane = tid & 15, g = tid >> 4;  // 16 groups of 16 lanes
    #pragma unroll
    for (int i = tid; i < BSZ * 16; i += 256) accl[i] = 0.f;
    __syncthreads();

    const int k = blockIdx.x, z = blockIdx.y;
    const int s0 = S[k], len = S[k + 1] - s0;
    const int b0 = s0 + (int)(((long long)len * z) / ZSL);
    const int e0 = s0 + (int)(((long long)len * (z + 1)) / ZSL);

    for (int base = b0; base < e0; base += 64) {
        #pragma unroll
        for (int q = 0; q < 4; ++q) {
            int i = base + q * 16 + g;
            if (i < e0) {
                unsigned int w = ebuf[i];
                int r = w & 0x1FFFF, c = w >> 17;
                float v = __half2float(tsh[(size_t)r * 16 + lane]);
                atomicAdd(&accl[c * 16 + lane], v);
            }
        }
    }
    __syncthreads();

    const int vbase = k << BSH;
    #pragma unroll
    for (int l = g; l < BSZ; l += 16) {
        int v = vbase + l;
        float pv = accl[l * 16 + lane];
        if (v < N && pv != 0.f) gAtomicAdd(&accg[(size_t)v * 16 + lane], pv);
    }
}

// ---- Finalize layer 1: h1 = relu(dinv*(acc+ts1)+b1); ts2h = half(dinv*(h1@W2)) ----
__global__ __launch_bounds__(256) void fin1(
    const float* __restrict__ accg, const __half* __restrict__ ts1h,
    const float* __restrict__ dinv, const float* __restrict__ b1,
    const float* __restrict__ W2, __half* __restrict__ ts2h, int N) {
    __shared__ float w2s[256];
    const int tid = threadIdx.x;
    if (tid < 256) w2s[tid] = W2[tid];
    __syncthreads();
    const int g = blockIdx.x * 16 + (tid >> 4);   // node
    const int lane = tid & 15;
    if (g >= N) return;
    float dv = dinv[g];
    float a = accg[(size_t)g * 16 + lane] + __half2float(ts1h[(size_t)g * 16 + lane]);
    float h = fmaxf(dv * a + b1[lane], 0.f);
    float o = 0.f;
    #pragma unroll
    for (int j = 0; j < 16; ++j)
        o = fmaf(__shfl(h, j, 16), w2s[j * 16 + lane], o);
    ts2h[(size_t)g * 16 + lane] = __float2half(dv * o);
}

// ---- Finalize layer 2: h2 = dinv*(acc+ts2)+b2 (fp16) ----
__global__ __launch_bounds__(256) void fin2(
    const float* __restrict__ accg, const __half* __restrict__ ts2h,
    const float* __restrict__ dinv, const float* __restrict__ b2,
    __half* __restrict__ h2h, int N) {
    const int tid = threadIdx.x;
    const int g = blockIdx.x * 16 + (tid >> 4);
    const int lane = tid & 15;
    if (g >= N) return;
    float a = accg[(size_t)g * 16 + lane] + __half2float(ts2h[(size_t)g * 16 + lane]);
    h2h[(size_t)g * 16 + lane] = __float2half(dinv[g] * a + b2[lane]);
}

// ---- Edge scores ----
__global__ void k_score(const int* __restrict__ row, const int* __restrict__ col,
                        const __half* __restrict__ h2h, float* __restrict__ out, int E) {
    int e = blockIdx.x * 256 + threadIdx.x;
    if (e < E) {
        union { uint4 u[2]; __half2 h[8]; } a, b;
        const uint4* pa = (const uint4*)(h2h + (size_t)row[e] * 16);
        const uint4* pb = (const uint4*)(h2h + (size_t)col[e] * 16);
        a.u[0] = pa[0]; a.u[1] = pa[1];
        b.u[0] = pb[0]; b.u[1] = pb[1];
        float d = 0.f;
        #pragma unroll
        for (int i = 0; i < 8; ++i) {
            float2 fa = __half22float2(a.h[i]);
            float2 fb = __half22float2(b.h[i]);
            d = fmaf(fa.x, fb.x, fmaf(fa.y, fb.y, d));
        }
        out[e] = 1.0f / (1.0f + __expf(-d));
    }
}

// ---------------- Fallback (R2 atomic path) ----------------
__global__ void k_countf(const int* __restrict__ col, float* __restrict__ deg, int E) {
    int e = blockIdx.x * 256 + threadIdx.x;
    if (e < E) atomicAdd(&deg[col[e]], 1.0f);
}
__global__ void k_dinvf(float* __restrict__ dinv, int N) {
    int v = blockIdx.x * 256 + threadIdx.x;
    if (v < N) dinv[v] = rsqrtf(dinv[v] + 1.0f);
}
__global__ __launch_bounds__(256) void k_gemm1f(
    const float* __restrict__ x, const float* __restrict__ W1,
    const float* __restrict__ dinv, float* __restrict__ ts, int N) {
    __shared__ float wsT[16 * 132];
    const int tid = threadIdx.x;
    for (int idx = tid; idx < 2048; idx += 256) {
        int k = idx >> 4, c = idx & 15;
        wsT[c * 132 + k] = W1[idx];
    }
    __syncthreads();
    const int n = blockIdx.x * 256 + tid;
    if (n >= N) return;
    const float4* xr = (const float4*)(x + (size_t)n * 128);
    float acc[16];
    #pragma unroll
    for (int c = 0; c < 16; ++c) acc[c] = 0.f;
    for (int k4 = 0; k4 < 32; ++k4) {
        float4 a = xr[k4];
        #pragma unroll
        for (int c = 0; c < 16; ++c) {
            const float4 w = *(const float4*)&wsT[c * 132 + k4 * 4];
            acc[c] = fmaf(a.x, w.x, fmaf(a.y, w.y, fmaf(a.z, w.z, fmaf(a.w, w.w, acc[c]))));
        }
    }
    float dv = dinv[n];
    float4* o = (float4*)(ts + (size_t)n * 16);
    #pragma unroll
    for (int q = 0; q < 4; ++q)
        o[q] = make_float4(acc[4*q] * dv, acc[4*q+1] * dv, acc[4*q+2] * dv, acc[4*q+3] * dv);
}
__global__ void k_scatter(const int* __restrict__ row, const int* __restrict__ col,
                          const float* __restrict__ ts, float* __restrict__ acc, int E) {
    int g = blockIdx.x * 256 + threadIdx.x;
    int e = g >> 4, c = g & 15;
    if (e < E) atomicAdd(&acc[(size_t)col[e] * 16 + c], ts[(size_t)row[e] * 16 + c]);
}
__global__ void k_finalize(float* __restrict__ acc, const float* __restrict__ ts,
                           const float* __restrict__ dinv, const float* __restrict__ b,
                           int N, int relu) {
    int g = blockIdx.x * 256 + threadIdx.x;
    int v = g >> 4, c = g & 15;
    if (v < N) {
        float h = dinv[v] * (acc[g] + ts[g]) + b[c];
        if (relu) h = fmaxf(h, 0.f);
        acc[g] = h;
    }
}
__global__ __launch_bounds__(256) void k_gemm2f(
    const float* __restrict__ h1, const float* __restrict__ W2,
    const float* __restrict__ dinv, float* __restrict__ ts2, int N) {
    __shared__ float hs[16 * 17];
    __shared__ float ws2[256];
    const int tid = threadIdx.x;
    const int base = blockIdx.x * 16;
    if (tid < 64) ((float4*)ws2)[tid] = ((const float4*)W2)[tid];
    if (tid >= 64 && tid < 128) {
        int t2 = tid - 64;
        float4 v4 = ((const float4*)(h1 + (size_t)base * 16))[t2];
        float* d = &hs[(t2 >> 2) * 17 + (t2 & 3) * 4];
        d[0] = v4.x; d[1] = v4.y; d[2] = v4.z; d[3] = v4.w;
    }
    __syncthreads();
    const int r = tid >> 4, c = tid & 15;
    float a = 0.f;
    #pragma unroll
    for (int kk = 0; kk < 16; ++kk) a = fmaf(hs[r * 17 + kk], ws2[kk * 16 + c], a);
    ts2[(size_t)(base + r) * 16 + c] = a * dinv[base + r];
}
__global__ void k_scoref(const int* __restrict__ row, const int* __restrict__ col,
                         const float* __restrict__ h2, float* __restrict__ out, int E) {
    int e = blockIdx.x * 256 + threadIdx.x;
    if (e < E) {
        const float4* a = (const float4*)(h2 + (size_t)row[e] * 16);
        const float4* b = (const float4*)(h2 + (size_t)col[e] * 16);
        float d = 0.f;
        #pragma unroll
        for (int i = 0; i < 4; ++i) {
            float4 u = a[i], v = b[i];
            d += u.x * v.x + u.y * v.y + u.z * v.z + u.w * v.w;
        }
        out[e] = 1.0f / (1.0f + __expf(-d));
    }
}

extern "C" void kernel_launch(void* const* d_in, const int* in_sizes, int n_in,
                              void* d_out, int out_size, void* d_ws, size_t ws_size,
                              hipStream_t stream) {
    const float* x  = (const float*)d_in[0];
    const int*   ei = (const int*)d_in[1];
    const float* W1 = (const float*)d_in[2];
    const float* b1 = (const float*)d_in[3];
    const float* W2 = (const float*)d_in[4];
    const float* b2 = (const float*)d_in[5];

    const int N = in_sizes[0] / 128;   // 100000
    const int E = in_sizes[1] / 2;     // 3200000
    const int* row = ei;
    const int* col = ei + E;
    float* out = (float*)d_out;

    const int NBUK = (N + BSZ - 1) / BSZ;   // 196
    const int CH = (E + PA_BLOCKS - 1) / PA_BLOCKS;

    char* ws = (char*)d_ws;
    size_t off = 0;
    auto alloc = [&](size_t bytes) { void* p = ws + off; off += (bytes + 255) & ~(size_t)255; return p; };
    float*  dinv = (float*)alloc((size_t)N * 4);
    __half* ts1h = (__half*)alloc((size_t)N * 32);     // also h2h after fin1
    __half* ts2h = (__half*)alloc((size_t)N * 32);
    float*  accg = (float*)alloc((size_t)N * 64);      // reused for both layers
    int*    M    = (int*)alloc((size_t)PA_BLOCKS * NBUK * 4);
    int*    T    = (int*)alloc((size_t)NBUK * 4);
    int*    S    = (int*)alloc((size_t)(NBUK + 1) * 4);
    unsigned int* ebuf = (unsigned int*)alloc((size_t)E * 4);
    const size_t need = off;

    if (N <= 131072 && NBUK <= 256 && ws_size >= need) {
        const size_t ldsA = (size_t)NBUK * 4;
        hipMemsetAsync(accg, 0, (size_t)N * 64, stream);
        pA <<<PA_BLOCKS, 512, ldsA, stream>>>(col, M, E, CH, NBUK);
        pB1<<<NBUK, 256, 0, stream>>>(M, T, NBUK);
        pB2<<<1, 256, 0, stream>>>(T, S, NBUK);
        pC <<<PA_BLOCKS, 512, ldsA, stream>>>(row, col, M, S, ebuf, E, CH, NBUK);
        pDeg<<<NBUK, 512, 0, stream>>>(ebuf, S, dinv, N);
        k_gemm1<<<(N + 255) / 256, 256, 0, stream>>>(x, W1, dinv, ts1h, N);
        pAgg<<<dim3(NBUK, ZSL), 256, 0, stream>>>(ebuf, S, ts1h, accg, N);
        fin1<<<(N + 15) / 16, 256, 0, stream>>>(accg, ts1h, dinv, b1, W2, ts2h, N);
        hipMemsetAsync(accg, 0, (size_t)N * 64, stream);
        pAgg<<<dim3(NBUK, ZSL), 256, 0, stream>>>(ebuf, S, ts2h, accg, N);
        __half* h2h = ts1h;   // ts1h dead after fin1
        fin2<<<(N + 15) / 16, 256, 0, stream>>>(accg, ts2h, dinv, b2, h2h, N);
        k_score<<<(E + 255) / 256, 256, 0, stream>>>(row, col, h2h, out, E);
    } else {
        // R2 fallback, fp32 buffers carved independently
        float* dinvF = (float*)ws;
        float* ts1F  = (float*)(ws + (size_t)N * 4);
        float* ts2F  = (float*)(ws + (size_t)N * 4 + (size_t)N * 64);
        hipMemsetAsync(dinvF, 0, (size_t)N * 4, stream);
        hipMemsetAsync(ts2F, 0, (size_t)N * 64, stream);
        k_countf<<<(E + 255) / 256, 256, 0, stream>>>(col, dinvF, E);
        k_dinvf<<<(N + 255) / 256, 256, 0, stream>>>(dinvF, N);
        k_gemm1f<<<(N + 255) / 256, 256, 0, stream>>>(x, W1, dinvF, ts1F, N);
        k_scatter<<<(E * 16) / 256, 256, 0, stream>>>(row, col, ts1F, ts2F, E);
        k_finalize<<<(N * 16 + 255) / 256, 256, 0, stream>>>(ts2F, ts1F, dinvF, b1, N, 1);
        k_gemm2f<<<N / 16, 256, 0, stream>>>(ts2F, W2, dinvF, ts1F, N);
        hipMemsetAsync(ts2F, 0, (size_t)N * 64, stream);
        k_scatter<<<(E * 16) / 256, 256, 0, stream>>>(row, col, ts1F, ts2F, E);
        k_finalize<<<(N * 16 + 255) / 256, 256, 0, stream>>>(ts2F, ts1F, dinvF, b2, N, 0);
        k_scoref<<<(E + 255) / 256, 256, 0, stream>>>(row, col, ts2F, out, E);
    }
}

// Round 6
// 378.382 us; speedup vs baseline: 2.5047x; 2.1645x over previous
//
#include <hip/hip_runtime.h>
#include <hip/hip_bf16.h>
#include <hip/hip_fp16.h>
#include <math.h>

// GCN link prediction. R6: full counting sort by destination column
// (bucket pass pA/pC + in-bucket pass pC2), then aggregation = segmented
// reduction over col-sorted edges: register accumulator, one coalesced 64B
// global atomic per run boundary (~0.1 atomic-instr/edge). No big-LDS
// accumulator (R5's pAgg was MLP-starved at 4 blocks/CU, 305us).
//   deg[v] = incount(col==v)+1 ; dinv = rsqrt(deg)
//   ts[v]  = (h[v]@W)*dinv[v]          (fp16 gather tables, L2-resident)
//   h'[c]  = act(dinv[c]*(sum_{e:col=c} ts[row_e] + ts[c]) + b)
//   score  = sigmoid(dot(h2[row], h2[col]))

#define BSH 9
#define BSZ 512
#define PA_BLOCKS 256

static __device__ __forceinline__ void gAtomicAdd(float* p, float v) {
#if defined(__HIP_DEVICE_COMPILE__)
    unsafeAtomicAdd(p, v);   // global_atomic_add_f32
#else
    atomicAdd(p, v);
#endif
}

// ---- Phase A: per-(chunk,bucket) histogram -> M[b][NBUK] ----
__global__ __launch_bounds__(512) void pA(const int* __restrict__ col,
                                          int* __restrict__ M, int E, int CH, int NBUK) {
    extern __shared__ int hist[];
    const int t = threadIdx.x, b = blockIdx.x;
    for (int i = t; i < NBUK; i += 512) hist[i] = 0;
    __syncthreads();
    const int s = b * CH, e = min(E, s + CH);
    for (int i = s + t; i < e; i += 512) atomicAdd(&hist[col[i] >> BSH], 1);
    __syncthreads();
    for (int i = t; i < NBUK; i += 512) M[b * NBUK + i] = hist[i];
}

// ---- Phase B1: per-bucket exclusive scan over chunks ----
__global__ __launch_bounds__(256) void pB1(int* __restrict__ M, int* __restrict__ T, int NBUK) {
    __shared__ int s[256];
    const int t = threadIdx.x, k = blockIdx.x;
    int own = M[t * NBUK + k];
    s[t] = own;
    __syncthreads();
    for (int d = 1; d < 256; d <<= 1) {
        int add = (t >= d) ? s[t - d] : 0;
        __syncthreads();
        s[t] += add;
        __syncthreads();
    }
    M[t * NBUK + k] = s[t] - own;
    if (t == 255) T[k] = s[255];
}

// ---- Phase B2: exclusive scan of bucket totals -> S[0..NBUK] ----
__global__ __launch_bounds__(256) void pB2(const int* __restrict__ T, int* __restrict__ S, int NBUK) {
    __shared__ int s[256];
    const int t = threadIdx.x;
    int own = (t < NBUK) ? T[t] : 0;
    s[t] = own;
    __syncthreads();
    for (int d = 1; d < 256; d <<= 1) {
        int add = (t >= d) ? s[t - d] : 0;
        __syncthreads();
        s[t] += add;
        __syncthreads();
    }
    if (t < NBUK) S[t] = s[t] - own;
    if (t == 255) S[NBUK] = s[255];
}

// ---- Phase C: bucket-place edges into ebuf, packed (lcol<<17)|row ----
__global__ __launch_bounds__(512) void pC(const int* __restrict__ row, const int* __restrict__ col,
                                          const int* __restrict__ M, const int* __restrict__ S,
                                          unsigned int* __restrict__ ebuf, int E, int CH, int NBUK) {
    extern __shared__ int cur[];
    const int t = threadIdx.x, b = blockIdx.x;
    for (int i = t; i < NBUK; i += 512) cur[i] = S[i] + M[b * NBUK + i];
    __syncthreads();
    const int s = b * CH, e = min(E, s + CH);
    for (int i = s + t; i < e; i += 512) {
        int c = col[i], r = row[i];
        int p = atomicAdd(&cur[c >> BSH], 1);
        ebuf[p] = ((unsigned int)(c & (BSZ - 1)) << 17) | (unsigned int)r;
    }
}

// ---- Phase C2: in-bucket counting sort by local col; also emits dinv ----
__global__ __launch_bounds__(512) void pC2(const unsigned int* __restrict__ ebuf,
                                           const int* __restrict__ S,
                                           unsigned int* __restrict__ ebuf2,
                                           float* __restrict__ dinv, int N) {
    __shared__ int h[BSZ], sc[BSZ], cur[BSZ];
    const int t = threadIdx.x, k = blockIdx.x;
    h[t] = 0;
    __syncthreads();
    const int s = S[k], e = S[k + 1];
    for (int i = s + t; i < e; i += 512) atomicAdd(&h[ebuf[i] >> 17], 1);
    __syncthreads();
    const int v = (k << BSH) + t;
    if (v < N) dinv[v] = rsqrtf((float)h[t] + 1.0f);
    sc[t] = h[t];
    __syncthreads();
    for (int d = 1; d < 512; d <<= 1) {
        int add = (t >= d) ? sc[t - d] : 0;
        __syncthreads();
        sc[t] += add;
        __syncthreads();
    }
    cur[t] = sc[t] - h[t];             // exclusive scan
    __syncthreads();
    for (int i = s + t; i < e; i += 512) {
        unsigned int w = ebuf[i];
        int p = atomicAdd(&cur[w >> 17], 1);
        ebuf2[s + p] = w;
    }
}

// ---- GEMM1: ts1h[v] = half((x[v] @ W1) * dinv[v]) ----
__global__ __launch_bounds__(256) void k_gemm1(
    const float* __restrict__ x, const float* __restrict__ W1,
    const float* __restrict__ dinv, __half* __restrict__ ts, int N) {
    __shared__ float wsT[16 * 132];
    const int tid = threadIdx.x;
    for (int idx = tid; idx < 2048; idx += 256) {
        int k = idx >> 4, c = idx & 15;
        wsT[c * 132 + k] = W1[idx];
    }
    __syncthreads();
    const int n = blockIdx.x * 256 + tid;
    if (n >= N) return;
    const float4* xr = (const float4*)(x + (size_t)n * 128);
    float acc[16];
    #pragma unroll
    for (int c = 0; c < 16; ++c) acc[c] = 0.f;
    #pragma unroll 4
    for (int k4 = 0; k4 < 32; ++k4) {
        float4 a = xr[k4];
        #pragma unroll
        for (int c = 0; c < 16; ++c) {
            const float4 w = *(const float4*)&wsT[c * 132 + k4 * 4];
            acc[c] = fmaf(a.x, w.x, fmaf(a.y, w.y, fmaf(a.z, w.z, fmaf(a.w, w.w, acc[c]))));
        }
    }
    float dv = dinv[n];
    union { __half h[16]; uint4 u[2]; } o;
    #pragma unroll
    for (int c = 0; c < 16; ++c) o.h[c] = __float2half(acc[c] * dv);
    uint4* dst = (uint4*)(ts + (size_t)n * 16);
    dst[0] = o.u[0]; dst[1] = o.u[1];
}

// ---- Segmented reduction over col-sorted edges ----
// 16 lanes per span of 16 consecutive edges; lane = channel. Preload all 16
// gathered values (16 independent loads in flight), then run-accumulate and
// flush one coalesced 64B atomic per run boundary.
__global__ __launch_bounds__(256) void pSeg(
    const unsigned int* __restrict__ ebuf2, const int* __restrict__ S,
    const __half* __restrict__ tsh, float* __restrict__ accg, int E, int NBUK) {
    extern __shared__ int sS[];        // NBUK+1 ints
    const int tid = threadIdx.x;
    for (int i = tid; i <= NBUK; i += 256) sS[i] = S[i];
    __syncthreads();

    const int lane = tid & 15;
    const int i0 = (blockIdx.x * 16 + (tid >> 4)) * 16;   // span start
    if (i0 >= E) return;
    const int cnt = min(16, E - i0);

    unsigned int w = (lane < cnt) ? ebuf2[i0 + lane] : 0u;

    unsigned int wv[16];
    #pragma unroll
    for (int j = 0; j < 16; ++j) wv[j] = __shfl(w, j, 16);

    float val[16];
    #pragma unroll
    for (int j = 0; j < 16; ++j) {
        int r = wv[j] & 0x1FFFF;
        val[j] = (j < cnt) ? __half2float(tsh[(size_t)r * 16 + lane]) : 0.f;
    }

    // bucket of i0 via binary search (uniform per group)
    int lo = 0, hi = NBUK - 1;
    while (lo < hi) { int mid = (lo + hi + 1) >> 1; if (sS[mid] <= i0) lo = mid; else hi = mid - 1; }
    int kk = lo;

    while (i0 >= sS[kk + 1]) ++kk;
    int ccur = (kk << BSH) + (int)(wv[0] >> 17);
    float acc = val[0];
    for (int j = 1; j < cnt; ++j) {
        int ij = i0 + j;
        while (ij >= sS[kk + 1]) ++kk;
        int cg = (kk << BSH) + (int)(wv[j] >> 17);
        if (cg == ccur) {
            acc += val[j];
        } else {
            gAtomicAdd(&accg[(size_t)ccur * 16 + lane], acc);
            acc = val[j];
            ccur = cg;
        }
    }
    gAtomicAdd(&accg[(size_t)ccur * 16 + lane], acc);
}

// ---- Finalize layer 1: h1 = relu(dinv*(acc+ts1)+b1); ts2h = half(dinv*(h1@W2)) ----
__global__ __launch_bounds__(256) void fin1(
    const float* __restrict__ accg, const __half* __restrict__ ts1h,
    const float* __restrict__ dinv, const float* __restrict__ b1,
    const float* __restrict__ W2, __half* __restrict__ ts2h, int N) {
    __shared__ float w2s[256];
    const int tid = threadIdx.x;
    w2s[tid] = W2[tid];
    __syncthreads();
    const int g = blockIdx.x * 16 + (tid >> 4);
    const int lane = tid & 15;
    if (g >= N) return;
    float dv = dinv[g];
    float a = accg[(size_t)g * 16 + lane] + __half2float(ts1h[(size_t)g * 16 + lane]);
    float h = fmaxf(dv * a + b1[lane], 0.f);
    float o = 0.f;
    #pragma unroll
    for (int j = 0; j < 16; ++j)
        o = fmaf(__shfl(h, j, 16), w2s[j * 16 + lane], o);
    ts2h[(size_t)g * 16 + lane] = __float2half(dv * o);
}

// ---- Finalize layer 2: h2 = dinv*(acc+ts2)+b2 (fp16) ----
__global__ __launch_bounds__(256) void fin2(
    const float* __restrict__ accg, const __half* __restrict__ ts2h,
    const float* __restrict__ dinv, const float* __restrict__ b2,
    __half* __restrict__ h2h, int N) {
    const int tid = threadIdx.x;
    const int g = blockIdx.x * 16 + (tid >> 4);
    const int lane = tid & 15;
    if (g >= N) return;
    float a = accg[(size_t)g * 16 + lane] + __half2float(ts2h[(size_t)g * 16 + lane]);
    h2h[(size_t)g * 16 + lane] = __float2half(dinv[g] * a + b2[lane]);
}

// ---- Edge scores ----
__global__ void k_score(const int* __restrict__ row, const int* __restrict__ col,
                        const __half* __restrict__ h2h, float* __restrict__ out, int E) {
    int e = blockIdx.x * 256 + threadIdx.x;
    if (e < E) {
        union { uint4 u[2]; __half2 h[8]; } a, b;
        const uint4* pa = (const uint4*)(h2h + (size_t)row[e] * 16);
        const uint4* pb = (const uint4*)(h2h + (size_t)col[e] * 16);
        a.u[0] = pa[0]; a.u[1] = pa[1];
        b.u[0] = pb[0]; b.u[1] = pb[1];
        float d = 0.f;
        #pragma unroll
        for (int i = 0; i < 8; ++i) {
            float2 fa = __half22float2(a.h[i]);
            float2 fb = __half22float2(b.h[i]);
            d = fmaf(fa.x, fb.x, fmaf(fa.y, fb.y, d));
        }
        out[e] = 1.0f / (1.0f + __expf(-d));
    }
}

// ---------------- Fallback (R2 atomic path) ----------------
__global__ void k_countf(const int* __restrict__ col, float* __restrict__ deg, int E) {
    int e = blockIdx.x * 256 + threadIdx.x;
    if (e < E) atomicAdd(&deg[col[e]], 1.0f);
}
__global__ void k_dinvf(float* __restrict__ dinv, int N) {
    int v = blockIdx.x * 256 + threadIdx.x;
    if (v < N) dinv[v] = rsqrtf(dinv[v] + 1.0f);
}
__global__ __launch_bounds__(256) void k_gemm1f(
    const float* __restrict__ x, const float* __restrict__ W1,
    const float* __restrict__ dinv, float* __restrict__ ts, int N) {
    __shared__ float wsT[16 * 132];
    const int tid = threadIdx.x;
    for (int idx = tid; idx < 2048; idx += 256) {
        int k = idx >> 4, c = idx & 15;
        wsT[c * 132 + k] = W1[idx];
    }
    __syncthreads();
    const int n = blockIdx.x * 256 + tid;
    if (n >= N) return;
    const float4* xr = (const float4*)(x + (size_t)n * 128);
    float acc[16];
    #pragma unroll
    for (int c = 0; c < 16; ++c) acc[c] = 0.f;
    for (int k4 = 0; k4 < 32; ++k4) {
        float4 a = xr[k4];
        #pragma unroll
        for (int c = 0; c < 16; ++c) {
            const float4 w = *(const float4*)&wsT[c * 132 + k4 * 4];
            acc[c] = fmaf(a.x, w.x, fmaf(a.y, w.y, fmaf(a.z, w.z, fmaf(a.w, w.w, acc[c]))));
        }
    }
    float dv = dinv[n];
    float4* o = (float4*)(ts + (size_t)n * 16);
    #pragma unroll
    for (int q = 0; q < 4; ++q)
        o[q] = make_float4(acc[4*q] * dv, acc[4*q+1] * dv, acc[4*q+2] * dv, acc[4*q+3] * dv);
}
__global__ void k_scatter(const int* __restrict__ row, const int* __restrict__ col,
                          const float* __restrict__ ts, float* __restrict__ acc, int E) {
    int g = blockIdx.x * 256 + threadIdx.x;
    int e = g >> 4, c = g & 15;
    if (e < E) atomicAdd(&acc[(size_t)col[e] * 16 + c], ts[(size_t)row[e] * 16 + c]);
}
__global__ void k_finalize(float* __restrict__ acc, const float* __restrict__ ts,
                           const float* __restrict__ dinv, const float* __restrict__ b,
                           int N, int relu) {
    int g = blockIdx.x * 256 + threadIdx.x;
    int v = g >> 4, c = g & 15;
    if (v < N) {
        float h = dinv[v] * (acc[g] + ts[g]) + b[c];
        if (relu) h = fmaxf(h, 0.f);
        acc[g] = h;
    }
}
__global__ __launch_bounds__(256) void k_gemm2f(
    const float* __restrict__ h1, const float* __restrict__ W2,
    const float* __restrict__ dinv, float* __restrict__ ts2, int N) {
    __shared__ float hs[16 * 17];
    __shared__ float ws2[256];
    const int tid = threadIdx.x;
    const int base = blockIdx.x * 16;
    if (tid < 64) ((float4*)ws2)[tid] = ((const float4*)W2)[tid];
    if (tid >= 64 && tid < 128) {
        int t2 = tid - 64;
        float4 v4 = ((const float4*)(h1 + (size_t)base * 16))[t2];
        float* d = &hs[(t2 >> 2) * 17 + (t2 & 3) * 4];
        d[0] = v4.x; d[1] = v4.y; d[2] = v4.z; d[3] = v4.w;
    }
    __syncthreads();
    const int r = tid >> 4, c = tid & 15;
    float a = 0.f;
    #pragma unroll
    for (int kk = 0; kk < 16; ++kk) a = fmaf(hs[r * 17 + kk], ws2[kk * 16 + c], a);
    ts2[(size_t)(base + r) * 16 + c] = a * dinv[base + r];
}
__global__ void k_scoref(const int* __restrict__ row, const int* __restrict__ col,
                         const float* __restrict__ h2, float* __restrict__ out, int E) {
    int e = blockIdx.x * 256 + threadIdx.x;
    if (e < E) {
        const float4* a = (const float4*)(h2 + (size_t)row[e] * 16);
        const float4* b = (const float4*)(h2 + (size_t)col[e] * 16);
        float d = 0.f;
        #pragma unroll
        for (int i = 0; i < 4; ++i) {
            float4 u = a[i], v = b[i];
            d += u.x * v.x + u.y * v.y + u.z * v.z + u.w * v.w;
        }
        out[e] = 1.0f / (1.0f + __expf(-d));
    }
}

extern "C" void kernel_launch(void* const* d_in, const int* in_sizes, int n_in,
                              void* d_out, int out_size, void* d_ws, size_t ws_size,
                              hipStream_t stream) {
    const float* x  = (const float*)d_in[0];
    const int*   ei = (const int*)d_in[1];
    const float* W1 = (const float*)d_in[2];
    const float* b1 = (const float*)d_in[3];
    const float* W2 = (const float*)d_in[4];
    const float* b2 = (const float*)d_in[5];

    const int N = in_sizes[0] / 128;   // 100000
    const int E = in_sizes[1] / 2;     // 3200000
    const int* row = ei;
    const int* col = ei + E;
    float* out = (float*)d_out;

    const int NBUK = (N + BSZ - 1) / BSZ;   // 196
    const int CH = (E + PA_BLOCKS - 1) / PA_BLOCKS;

    char* ws = (char*)d_ws;
    size_t off = 0;
    auto alloc = [&](size_t bytes) { void* p = ws + off; off += (bytes + 255) & ~(size_t)255; return p; };
    float*  dinv = (float*)alloc((size_t)N * 4);
    __half* ts1h = (__half*)alloc((size_t)N * 32);     // also h2h after fin1
    __half* ts2h = (__half*)alloc((size_t)N * 32);
    float*  accg = (float*)alloc((size_t)N * 64);
    int*    M    = (int*)alloc((size_t)PA_BLOCKS * NBUK * 4);
    int*    T    = (int*)alloc((size_t)NBUK * 4);
    int*    S    = (int*)alloc((size_t)(NBUK + 1) * 4);
    unsigned int* ebuf  = (unsigned int*)alloc((size_t)E * 4);
    unsigned int* ebuf2 = (unsigned int*)alloc((size_t)E * 4);
    const size_t need = off;    // ~39.7 MB at N=100k, E=3.2M

    if (N <= 131072 && NBUK <= 256 && ws_size >= need) {
        const size_t ldsA = (size_t)NBUK * 4;
        const size_t ldsS = (size_t)(NBUK + 1) * 4;
        hipMemsetAsync(accg, 0, (size_t)N * 64, stream);
        pA <<<PA_BLOCKS, 512, ldsA, stream>>>(col, M, E, CH, NBUK);
        pB1<<<NBUK, 256, 0, stream>>>(M, T, NBUK);
        pB2<<<1, 256, 0, stream>>>(T, S, NBUK);
        pC <<<PA_BLOCKS, 512, ldsA, stream>>>(row, col, M, S, ebuf, E, CH, NBUK);
        pC2<<<NBUK, 512, 0, stream>>>(ebuf, S, ebuf2, dinv, N);
        k_gemm1<<<(N + 255) / 256, 256, 0, stream>>>(x, W1, dinv, ts1h, N);
        pSeg<<<(E + 4095) / 4096 * 16, 256, ldsS, stream>>>(ebuf2, S, ts1h, accg, E, NBUK);
        fin1<<<(N + 15) / 16, 256, 0, stream>>>(accg, ts1h, dinv, b1, W2, ts2h, N);
        hipMemsetAsync(accg, 0, (size_t)N * 64, stream);
        pSeg<<<(E + 4095) / 4096 * 16, 256, ldsS, stream>>>(ebuf2, S, ts2h, accg, E, NBUK);
        __half* h2h = ts1h;   // ts1h dead after fin1
        fin2<<<(N + 15) / 16, 256, 0, stream>>>(accg, ts2h, dinv, b2, h2h, N);
        k_score<<<(E + 255) / 256, 256, 0, stream>>>(row, col, h2h, out, E);
    } else {
        // R2 fallback, fp32 buffers carved independently
        float* dinvF = (float*)ws;
        float* ts1F  = (float*)(ws + (size_t)N * 4);
        float* ts2F  = (float*)(ws + (size_t)N * 4 + (size_t)N * 64);
        hipMemsetAsync(dinvF, 0, (size_t)N * 4, stream);
        hipMemsetAsync(ts2F, 0, (size_t)N * 64, stream);
        k_countf<<<(E + 255) / 256, 256, 0, stream>>>(col, dinvF, E);
        k_dinvf<<<(N + 255) / 256, 256, 0, stream>>>(dinvF, N);
        k_gemm1f<<<(N + 255) / 256, 256, 0, stream>>>(x, W1, dinvF, ts1F, N);
        k_scatter<<<(E * 16) / 256, 256, 0, stream>>>(row, col, ts1F, ts2F, E);
        k_finalize<<<(N * 16 + 255) / 256, 256, 0, stream>>>(ts2F, ts1F, dinvF, b1, N, 1);
        k_gemm2f<<<N / 16, 256, 0, stream>>>(ts2F, W2, dinvF, ts1F, N);
        hipMemsetAsync(ts2F, 0, (size_t)N * 64, stream);
        k_scatter<<<(E * 16) / 256, 256, 0, stream>>>(row, col, ts1F, ts2F, E);
        k_finalize<<<(N * 16 + 255) / 256, 256, 0, stream>>>(ts2F, ts1F, dinvF, b2, N, 0);
        k_scoref<<<(E + 255) / 256, 256, 0, stream>>>(row, col, ts2F, out, E);
    }
}

// Round 7
// 282.575 us; speedup vs baseline: 3.3539x; 1.3391x over previous
//
#include <hip/hip_runtime.h>
#include <hip/hip_bf16.h>
#include <hip/hip_fp16.h>
#include <math.h>

// GCN link prediction. R7: full counting sort by destination column
// (pA/pB/pC bucket pass + pC2 in-bucket pass which also emits CSR start[] and
// dinv), then aggregation = per-node CSR gather (16 lanes = channels, register
// accumulator, fused epilogue). No atomics, no accumulator buffer, no memsets.
//   deg[v] = incount(col==v)+1 ; dinv = rsqrt(deg)
//   ts[v]  = (h[v]@W)*dinv[v]          (fp16 gather tables, L2-resident)
//   h'[c]  = act(dinv[c]*(sum_{e:col=c} ts[row_e] + ts[c]) + b)
//   score  = sigmoid(dot(h2[row], h2[col]))

#define BSH 9
#define BSZ 512
#define PA_BLOCKS 256

// ---- Phase A: per-(chunk,bucket) histogram -> M[b][NBUK] ----
__global__ __launch_bounds__(512) void pA(const int* __restrict__ col,
                                          int* __restrict__ M, int E, int CH, int NBUK) {
    extern __shared__ int hist[];
    const int t = threadIdx.x, b = blockIdx.x;
    for (int i = t; i < NBUK; i += 512) hist[i] = 0;
    __syncthreads();
    const int s = b * CH, e = min(E, s + CH);
    for (int i = s + t; i < e; i += 512) atomicAdd(&hist[col[i] >> BSH], 1);
    __syncthreads();
    for (int i = t; i < NBUK; i += 512) M[b * NBUK + i] = hist[i];
}

// ---- Phase B1: per-bucket exclusive scan over chunks ----
__global__ __launch_bounds__(256) void pB1(int* __restrict__ M, int* __restrict__ T, int NBUK) {
    __shared__ int s[256];
    const int t = threadIdx.x, k = blockIdx.x;
    int own = M[t * NBUK + k];
    s[t] = own;
    __syncthreads();
    for (int d = 1; d < 256; d <<= 1) {
        int add = (t >= d) ? s[t - d] : 0;
        __syncthreads();
        s[t] += add;
        __syncthreads();
    }
    M[t * NBUK + k] = s[t] - own;
    if (t == 255) T[k] = s[255];
}

// ---- Phase B2: exclusive scan of bucket totals -> S[0..NBUK] ----
__global__ __launch_bounds__(256) void pB2(const int* __restrict__ T, int* __restrict__ S, int NBUK) {
    __shared__ int s[256];
    const int t = threadIdx.x;
    int own = (t < NBUK) ? T[t] : 0;
    s[t] = own;
    __syncthreads();
    for (int d = 1; d < 256; d <<= 1) {
        int add = (t >= d) ? s[t - d] : 0;
        __syncthreads();
        s[t] += add;
        __syncthreads();
    }
    if (t < NBUK) S[t] = s[t] - own;
    if (t == 255) S[NBUK] = s[255];
}

// ---- Phase C: bucket-place edges into ebuf, packed (lcol<<17)|row ----
__global__ __launch_bounds__(512) void pC(const int* __restrict__ row, const int* __restrict__ col,
                                          const int* __restrict__ M, const int* __restrict__ S,
                                          unsigned int* __restrict__ ebuf, int E, int CH, int NBUK) {
    extern __shared__ int cur[];
    const int t = threadIdx.x, b = blockIdx.x;
    for (int i = t; i < NBUK; i += 512) cur[i] = S[i] + M[b * NBUK + i];
    __syncthreads();
    const int s = b * CH, e = min(E, s + CH);
    for (int i = s + t; i < e; i += 512) {
        int c = col[i], r = row[i];
        int p = atomicAdd(&cur[c >> BSH], 1);
        ebuf[p] = ((unsigned int)(c & (BSZ - 1)) << 17) | (unsigned int)r;
    }
}

// ---- Phase C2: in-bucket counting sort by local col; emits dinv and CSR start ----
__global__ __launch_bounds__(512) void pC2(const unsigned int* __restrict__ ebuf,
                                           const int* __restrict__ S,
                                           unsigned int* __restrict__ ebuf2,
                                           float* __restrict__ dinv,
                                           int* __restrict__ start, int N) {
    __shared__ int h[BSZ], sc[BSZ], cur[BSZ];
    const int t = threadIdx.x, k = blockIdx.x;
    h[t] = 0;
    __syncthreads();
    const int s = S[k], e = S[k + 1];
    for (int i = s + t; i < e; i += 512) atomicAdd(&h[ebuf[i] >> 17], 1);
    __syncthreads();
    sc[t] = h[t];
    __syncthreads();
    for (int d = 1; d < 512; d <<= 1) {
        int add = (t >= d) ? sc[t - d] : 0;
        __syncthreads();
        sc[t] += add;
        __syncthreads();
    }
    cur[t] = sc[t] - h[t];             // exclusive scan
    const int v = (k << BSH) + t;
    if (v < N) {
        dinv[v] = rsqrtf((float)h[t] + 1.0f);
        start[v] = s + cur[t];
    }
    __syncthreads();
    for (int i = s + t; i < e; i += 512) {
        unsigned int w = ebuf[i];
        int p = atomicAdd(&cur[w >> 17], 1);
        ebuf2[s + p] = w;
    }
}

__global__ void kTail(int* __restrict__ start, int N, int E) { start[N] = E; }

// ---- GEMM1: ts1h[v] = half((x[v] @ W1) * dinv[v]) ----
__global__ __launch_bounds__(256) void k_gemm1(
    const float* __restrict__ x, const float* __restrict__ W1,
    const float* __restrict__ dinv, __half* __restrict__ ts, int N) {
    __shared__ float wsT[16 * 132];
    const int tid = threadIdx.x;
    for (int idx = tid; idx < 2048; idx += 256) {
        int k = idx >> 4, c = idx & 15;
        wsT[c * 132 + k] = W1[idx];
    }
    __syncthreads();
    const int n = blockIdx.x * 256 + tid;
    if (n >= N) return;
    const float4* xr = (const float4*)(x + (size_t)n * 128);
    float acc[16];
    #pragma unroll
    for (int c = 0; c < 16; ++c) acc[c] = 0.f;
    #pragma unroll 4
    for (int k4 = 0; k4 < 32; ++k4) {
        float4 a = xr[k4];
        #pragma unroll
        for (int c = 0; c < 16; ++c) {
            const float4 w = *(const float4*)&wsT[c * 132 + k4 * 4];
            acc[c] = fmaf(a.x, w.x, fmaf(a.y, w.y, fmaf(a.z, w.z, fmaf(a.w, w.w, acc[c]))));
        }
    }
    float dv = dinv[n];
    union { __half h[16]; uint4 u[2]; } o;
    #pragma unroll
    for (int c = 0; c < 16; ++c) o.h[c] = __float2half(acc[c] * dv);
    uint4* dst = (uint4*)(ts + (size_t)n * 16);
    dst[0] = o.u[0]; dst[1] = o.u[1];
}

// ---- Layer-1 aggregation: per-node CSR gather + fused bias/ReLU + 16x16 W2 ----
__global__ __launch_bounds__(256) void pGat1(
    const unsigned int* __restrict__ ebuf2, const int* __restrict__ start,
    const __half* __restrict__ ts1h, const float* __restrict__ dinv,
    const float* __restrict__ b1, const float* __restrict__ W2,
    __half* __restrict__ ts2h, int N) {
    __shared__ float w2s[256];
    const int tid = threadIdx.x;
    w2s[tid] = W2[tid];
    __syncthreads();
    const int lane = tid & 15;
    const int v = blockIdx.x * 16 + (tid >> 4);
    if (v >= N) return;
    const int s = start[v], e = start[v + 1];
    float sum = 0.f;
    int i = s;
    for (; i + 4 <= e; i += 4) {
        int r0 = ebuf2[i]     & 0x1FFFF;
        int r1 = ebuf2[i + 1] & 0x1FFFF;
        int r2 = ebuf2[i + 2] & 0x1FFFF;
        int r3 = ebuf2[i + 3] & 0x1FFFF;
        float v0 = __half2float(ts1h[(size_t)r0 * 16 + lane]);
        float v1 = __half2float(ts1h[(size_t)r1 * 16 + lane]);
        float v2 = __half2float(ts1h[(size_t)r2 * 16 + lane]);
        float v3 = __half2float(ts1h[(size_t)r3 * 16 + lane]);
        sum += (v0 + v1) + (v2 + v3);
    }
    for (; i < e; ++i) {
        int r = ebuf2[i] & 0x1FFFF;
        sum += __half2float(ts1h[(size_t)r * 16 + lane]);
    }
    float dv = dinv[v];
    float h = fmaxf(dv * (sum + __half2float(ts1h[(size_t)v * 16 + lane])) + b1[lane], 0.f);
    float o = 0.f;
    #pragma unroll
    for (int j = 0; j < 16; ++j)
        o = fmaf(__shfl(h, j, 16), w2s[j * 16 + lane], o);
    ts2h[(size_t)v * 16 + lane] = __float2half(dv * o);
}

// ---- Layer-2 aggregation: per-node CSR gather + final bias -> h2 (fp16) ----
__global__ __launch_bounds__(256) void pGat2(
    const unsigned int* __restrict__ ebuf2, const int* __restrict__ start,
    const __half* __restrict__ ts2h, const float* __restrict__ dinv,
    const float* __restrict__ b2, __half* __restrict__ h2h, int N) {
    const int tid = threadIdx.x;
    const int lane = tid & 15;
    const int v = blockIdx.x * 16 + (tid >> 4);
    if (v >= N) return;
    const int s = start[v], e = start[v + 1];
    float sum = 0.f;
    int i = s;
    for (; i + 4 <= e; i += 4) {
        int r0 = ebuf2[i]     & 0x1FFFF;
        int r1 = ebuf2[i + 1] & 0x1FFFF;
        int r2 = ebuf2[i + 2] & 0x1FFFF;
        int r3 = ebuf2[i + 3] & 0x1FFFF;
        float v0 = __half2float(ts2h[(size_t)r0 * 16 + lane]);
        float v1 = __half2float(ts2h[(size_t)r1 * 16 + lane]);
        float v2 = __half2float(ts2h[(size_t)r2 * 16 + lane]);
        float v3 = __half2float(ts2h[(size_t)r3 * 16 + lane]);
        sum += (v0 + v1) + (v2 + v3);
    }
    for (; i < e; ++i) {
        int r = ebuf2[i] & 0x1FFFF;
        sum += __half2float(ts2h[(size_t)r * 16 + lane]);
    }
    float a = sum + __half2float(ts2h[(size_t)v * 16 + lane]);
    h2h[(size_t)v * 16 + lane] = __float2half(dinv[v] * a + b2[lane]);
}

// ---- Edge scores ----
__global__ void k_score(const int* __restrict__ row, const int* __restrict__ col,
                        const __half* __restrict__ h2h, float* __restrict__ out, int E) {
    int e = blockIdx.x * 256 + threadIdx.x;
    if (e < E) {
        union { uint4 u[2]; __half2 h[8]; } a, b;
        const uint4* pa = (const uint4*)(h2h + (size_t)row[e] * 16);
        const uint4* pb = (const uint4*)(h2h + (size_t)col[e] * 16);
        a.u[0] = pa[0]; a.u[1] = pa[1];
        b.u[0] = pb[0]; b.u[1] = pb[1];
        float d = 0.f;
        #pragma unroll
        for (int i = 0; i < 8; ++i) {
            float2 fa = __half22float2(a.h[i]);
            float2 fb = __half22float2(b.h[i]);
            d = fmaf(fa.x, fb.x, fmaf(fa.y, fb.y, d));
        }
        out[e] = 1.0f / (1.0f + __expf(-d));
    }
}

// ---------------- Fallback (R2 atomic path) ----------------
__global__ void k_countf(const int* __restrict__ col, float* __restrict__ deg, int E) {
    int e = blockIdx.x * 256 + threadIdx.x;
    if (e < E) atomicAdd(&deg[col[e]], 1.0f);
}
__global__ void k_dinvf(float* __restrict__ dinv, int N) {
    int v = blockIdx.x * 256 + threadIdx.x;
    if (v < N) dinv[v] = rsqrtf(dinv[v] + 1.0f);
}
__global__ __launch_bounds__(256) void k_gemm1f(
    const float* __restrict__ x, const float* __restrict__ W1,
    const float* __restrict__ dinv, float* __restrict__ ts, int N) {
    __shared__ float wsT[16 * 132];
    const int tid = threadIdx.x;
    for (int idx = tid; idx < 2048; idx += 256) {
        int k = idx >> 4, c = idx & 15;
        wsT[c * 132 + k] = W1[idx];
    }
    __syncthreads();
    const int n = blockIdx.x * 256 + tid;
    if (n >= N) return;
    const float4* xr = (const float4*)(x + (size_t)n * 128);
    float acc[16];
    #pragma unroll
    for (int c = 0; c < 16; ++c) acc[c] = 0.f;
    for (int k4 = 0; k4 < 32; ++k4) {
        float4 a = xr[k4];
        #pragma unroll
        for (int c = 0; c < 16; ++c) {
            const float4 w = *(const float4*)&wsT[c * 132 + k4 * 4];
            acc[c] = fmaf(a.x, w.x, fmaf(a.y, w.y, fmaf(a.z, w.z, fmaf(a.w, w.w, acc[c]))));
        }
    }
    float dv = dinv[n];
    float4* o = (float4*)(ts + (size_t)n * 16);
    #pragma unroll
    for (int q = 0; q < 4; ++q)
        o[q] = make_float4(acc[4*q] * dv, acc[4*q+1] * dv, acc[4*q+2] * dv, acc[4*q+3] * dv);
}
__global__ void k_scatter(const int* __restrict__ row, const int* __restrict__ col,
                          const float* __restrict__ ts, float* __restrict__ acc, int E) {
    int g = blockIdx.x * 256 + threadIdx.x;
    int e = g >> 4, c = g & 15;
    if (e < E) atomicAdd(&acc[(size_t)col[e] * 16 + c], ts[(size_t)row[e] * 16 + c]);
}
__global__ void k_finalize(float* __restrict__ acc, const float* __restrict__ ts,
                           const float* __restrict__ dinv, const float* __restrict__ b,
                           int N, int relu) {
    int g = blockIdx.x * 256 + threadIdx.x;
    int v = g >> 4, c = g & 15;
    if (v < N) {
        float h = dinv[v] * (acc[g] + ts[g]) + b[c];
        if (relu) h = fmaxf(h, 0.f);
        acc[g] = h;
    }
}
__global__ __launch_bounds__(256) void k_gemm2f(
    const float* __restrict__ h1, const float* __restrict__ W2,
    const float* __restrict__ dinv, float* __restrict__ ts2, int N) {
    __shared__ float hs[16 * 17];
    __shared__ float ws2[256];
    const int tid = threadIdx.x;
    const int base = blockIdx.x * 16;
    if (tid < 64) ((float4*)ws2)[tid] = ((const float4*)W2)[tid];
    if (tid >= 64 && tid < 128) {
        int t2 = tid - 64;
        float4 v4 = ((const float4*)(h1 + (size_t)base * 16))[t2];
        float* d = &hs[(t2 >> 2) * 17 + (t2 & 3) * 4];
        d[0] = v4.x; d[1] = v4.y; d[2] = v4.z; d[3] = v4.w;
    }
    __syncthreads();
    const int r = tid >> 4, c = tid & 15;
    float a = 0.f;
    #pragma unroll
    for (int kk = 0; kk < 16; ++kk) a = fmaf(hs[r * 17 + kk], ws2[kk * 16 + c], a);
    ts2[(size_t)(base + r) * 16 + c] = a * dinv[base + r];
}
__global__ void k_scoref(const int* __restrict__ row, const int* __restrict__ col,
                         const float* __restrict__ h2, float* __restrict__ out, int E) {
    int e = blockIdx.x * 256 + threadIdx.x;
    if (e < E) {
        const float4* a = (const float4*)(h2 + (size_t)row[e] * 16);
        const float4* b = (const float4*)(h2 + (size_t)col[e] * 16);
        float d = 0.f;
        #pragma unroll
        for (int i = 0; i < 4; ++i) {
            float4 u = a[i], v = b[i];
            d += u.x * v.x + u.y * v.y + u.z * v.z + u.w * v.w;
        }
        out[e] = 1.0f / (1.0f + __expf(-d));
    }
}

extern "C" void kernel_launch(void* const* d_in, const int* in_sizes, int n_in,
                              void* d_out, int out_size, void* d_ws, size_t ws_size,
                              hipStream_t stream) {
    const float* x  = (const float*)d_in[0];
    const int*   ei = (const int*)d_in[1];
    const float* W1 = (const float*)d_in[2];
    const float* b1 = (const float*)d_in[3];
    const float* W2 = (const float*)d_in[4];
    const float* b2 = (const float*)d_in[5];

    const int N = in_sizes[0] / 128;   // 100000
    const int E = in_sizes[1] / 2;     // 3200000
    const int* row = ei;
    const int* col = ei + E;
    float* out = (float*)d_out;

    const int NBUK = (N + BSZ - 1) / BSZ;   // 196
    const int CH = (E + PA_BLOCKS - 1) / PA_BLOCKS;

    char* ws = (char*)d_ws;
    size_t off = 0;
    auto alloc = [&](size_t bytes) { void* p = ws + off; off += (bytes + 255) & ~(size_t)255; return p; };
    float*  dinv  = (float*)alloc((size_t)N * 4);
    __half* ts1h  = (__half*)alloc((size_t)N * 32);    // also h2h after pGat1
    __half* ts2h  = (__half*)alloc((size_t)N * 32);
    int*    start = (int*)alloc((size_t)(N + 1) * 4);
    int*    M     = (int*)alloc((size_t)PA_BLOCKS * NBUK * 4);
    int*    T     = (int*)alloc((size_t)NBUK * 4);
    int*    S     = (int*)alloc((size_t)(NBUK + 1) * 4);
    unsigned int* ebuf  = (unsigned int*)alloc((size_t)E * 4);
    unsigned int* ebuf2 = (unsigned int*)alloc((size_t)E * 4);
    const size_t need = off;    // ~33.5 MB at N=100k, E=3.2M

    if (N <= 131072 && NBUK <= 256 && ws_size >= need) {
        const size_t ldsA = (size_t)NBUK * 4;
        pA <<<PA_BLOCKS, 512, ldsA, stream>>>(col, M, E, CH, NBUK);
        pB1<<<NBUK, 256, 0, stream>>>(M, T, NBUK);
        pB2<<<1, 256, 0, stream>>>(T, S, NBUK);
        pC <<<PA_BLOCKS, 512, ldsA, stream>>>(row, col, M, S, ebuf, E, CH, NBUK);
        pC2<<<NBUK, 512, 0, stream>>>(ebuf, S, ebuf2, dinv, start, N);
        kTail<<<1, 1, 0, stream>>>(start, N, E);
        k_gemm1<<<(N + 255) / 256, 256, 0, stream>>>(x, W1, dinv, ts1h, N);
        pGat1<<<(N + 15) / 16, 256, 0, stream>>>(ebuf2, start, ts1h, dinv, b1, W2, ts2h, N);
        __half* h2h = ts1h;   // ts1h dead after pGat1
        pGat2<<<(N + 15) / 16, 256, 0, stream>>>(ebuf2, start, ts2h, dinv, b2, h2h, N);
        k_score<<<(E + 255) / 256, 256, 0, stream>>>(row, col, h2h, out, E);
    } else {
        // R2 fallback, fp32 buffers carved independently
        float* dinvF = (float*)ws;
        float* ts1F  = (float*)(ws + (size_t)N * 4);
        float* ts2F  = (float*)(ws + (size_t)N * 4 + (size_t)N * 64);
        hipMemsetAsync(dinvF, 0, (size_t)N * 4, stream);
        hipMemsetAsync(ts2F, 0, (size_t)N * 64, stream);
        k_countf<<<(E + 255) / 256, 256, 0, stream>>>(col, dinvF, E);
        k_dinvf<<<(N + 255) / 256, 256, 0, stream>>>(dinvF, N);
        k_gemm1f<<<(N + 255) / 256, 256, 0, stream>>>(x, W1, dinvF, ts1F, N);
        k_scatter<<<(E * 16) / 256, 256, 0, stream>>>(row, col, ts1F, ts2F, E);
        k_finalize<<<(N * 16 + 255) / 256, 256, 0, stream>>>(ts2F, ts1F, dinvF, b1, N, 1);
        k_gemm2f<<<N / 16, 256, 0, stream>>>(ts2F, W2, dinvF, ts1F, N);
        hipMemsetAsync(ts2F, 0, (size_t)N * 64, stream);
        k_scatter<<<(E * 16) / 256, 256, 0, stream>>>(row, col, ts1F, ts2F, E);
        k_finalize<<<(N * 16 + 255) / 256, 256, 0, stream>>>(ts2F, ts1F, dinvF, b2, N, 0);
        k_scoref<<<(E + 255) / 256, 256, 0, stream>>>(row, col, ts2F, out, E);
    }
}